// Round 1
// baseline (220.825 us; speedup 1.0000x reference)
//
#include <hip/hip_runtime.h>
#include <hip/hip_bf16.h>

// L=2048, E=512, E_PT=300, H=16. All inputs f32. Output f32 [2048,512].
//
// R18 = R17 (proven 205us) + split-K=2 on the gram GEMM:
//  - gram counters showed Occupancy 18% / MfmaUtil 12% / HBM 17%: pure
//    latency-bound at 2.06 blocks/CU (528 live triangle blocks). Split-K=2
//    via the R14-proven SPLITX path -> 1056 live blocks (~4.1/CU), one
//    dispatch, two symmetric partials (S, P1g), flat combiner S += P1g.
//  - workspace: P1g [36.44M, 53.22M); norms moved to 53.22M (peak 53.35MB,
//    within the 53.4MB proven by R12). GCN P0/P1 keep old offsets (overlap
//    P1g only after P1g is dead). 10 -> 11 dispatches.
// Gram math unchanged (f32 accum, one extra partial-sum rounding << 5.5e-4
// repair window). Everything else = R17 verbatim.

typedef __attribute__((ext_vector_type(8))) short bf16x8;
typedef __attribute__((ext_vector_type(4))) float f32x4;

#define L_DIM 2048
#define EPT 300
#define H_DIM 16
#define KDIM 4800
#define WINDOW 5.5e-4f

// ---------------- 1) Y + norms ----------------
__global__ void compute_y_kernel(const float* __restrict__ xpt,
                                 const float* __restrict__ Wpt,
                                 __hip_bfloat16* __restrict__ Y,
                                 float* __restrict__ norms) {
  int gw = (blockIdx.x * 256 + threadIdx.x) >> 6;  // wave id = (i,h) pair
  int lane = threadIdx.x & 63;
  int i = gw >> 4, h = gw & 15;
  const float* x = xpt + i * EPT;
  const float* w = Wpt + h * EPT;
  float v[5];
  float ss = 0.f;
#pragma unroll
  for (int t = 0; t < 5; ++t) {
    int e = lane + 64 * t;
    float val = 0.f;
    if (e < EPT) {
      float we = w[e];
      val = x[e] * we * we;
    }
    v[t] = val;
    ss += val * val;
  }
#pragma unroll
  for (int o = 32; o >= 1; o >>= 1) ss += __shfl_xor(ss, o, 64);
  float n = fmaxf(sqrtf(ss), 1e-12f);
  if (lane == 0) norms[i * H_DIM + h] = n;
  float scale = 0.25f / n;  // 1/(norm*sqrt(H))
#pragma unroll
  for (int t = 0; t < 5; ++t) {
    int e = lane + 64 * t;
    if (e < EPT) Y[(size_t)i * KDIM + h * EPT + e] = __float2bfloat16(v[t] * scale);
  }
}

// ---------------- 2) bt-GEMM: C = A * B^T (R14/R16-proven) ----------------
template <int BM, int BN, bool RELU, bool OUT_BF16, bool MIRROR, bool SPLITX>
__global__ __launch_bounds__(256) void gemm_bt(const __hip_bfloat16* __restrict__ A,
                                               const __hip_bfloat16* __restrict__ B,
                                               void* __restrict__ C0v, void* __restrict__ C1v,
                                               int M, int N, int K) {
  constexpr int WMG = BM / 64;
  constexpr int WNG = 4 / WMG;
  constexpr int NC = BN / (16 * WNG);
  int bx = blockIdx.x;
  int kbeg = 0, kend = K;
  if (SPLITX) {
    const int xhalf = gridDim.x >> 1;
    const int khalf = ((K >> 1) + 63) & ~63;
    if (bx >= xhalf) {
      bx -= xhalf;
      kbeg = khalf;
    } else {
      kend = khalf;
    }
  }
  const int row0 = blockIdx.y * BM, col0 = bx * BN;
  if (MIRROR && col0 + BN <= row0) return;  // fully below diagonal
  const bool do_mirror = MIRROR && (col0 > row0);
  __shared__ __attribute__((aligned(16))) __hip_bfloat16 As[2][BM * 64];
  __shared__ __attribute__((aligned(16))) __hip_bfloat16 Bs[2][BN * 64];
  const int tid = threadIdx.x;
  const int lane = tid & 63;
  const int wave = tid >> 6;
  const int wm = wave / WNG, wn = wave % WNG;
  const int r = lane & 15, q = lane >> 4;
  const int srow = tid >> 3;
  const int schunk = (tid & 7) ^ (srow & 7);

  f32x4 acc[4][NC];
#pragma unroll
  for (int a = 0; a < 4; ++a)
#pragma unroll
    for (int b = 0; b < NC; ++b) {
      f32x4 z = {0.f, 0.f, 0.f, 0.f};
      acc[a][b] = z;
    }

  const int niter = (kend - kbeg) >> 6;

#define STAGE(bufi, k0)                                                                       \
  {                                                                                           \
    _Pragma("unroll") for (int it = 0; it < BM / 32; ++it) {                                  \
      __builtin_amdgcn_global_load_lds(                                                       \
          (const __attribute__((address_space(1))) void*)(A + (size_t)(row0 + it * 32 + srow) * K + \
                                                          (k0) + schunk * 8),                 \
          (__attribute__((address_space(3))) void*)(&As[bufi][(it * 256 + tid) * 8]), 16, 0, 0); \
    }                                                                                         \
    _Pragma("unroll") for (int it = 0; it < BN / 32; ++it) {                                  \
      __builtin_amdgcn_global_load_lds(                                                       \
          (const __attribute__((address_space(1))) void*)(B + (size_t)(col0 + it * 32 + srow) * K + \
                                                          (k0) + schunk * 8),                 \
          (__attribute__((address_space(3))) void*)(&Bs[bufi][(it * 256 + tid) * 8]), 16, 0, 0); \
    }                                                                                         \
  }

  STAGE(0, kbeg)
  for (int k = 0; k < niter; ++k) {
    __syncthreads();
    if (k + 1 < niter) STAGE((k + 1) & 1, kbeg + ((k + 1) << 6))
    const __hip_bfloat16* as = As[k & 1];
    const __hip_bfloat16* bs = Bs[k & 1];
#pragma unroll
    for (int kk = 0; kk < 2; ++kk) {
      const int ch = ((kk * 4 + q) ^ (r & 7)) * 8;
      bf16x8 af[4], bfr[NC];
#pragma unroll
      for (int t = 0; t < 4; ++t)
        af[t] = *(const bf16x8*)(as + (wm * 64 + t * 16 + r) * 64 + ch);
#pragma unroll
      for (int c = 0; c < NC; ++c)
        bfr[c] = *(const bf16x8*)(bs + (wn * 16 * NC + c * 16 + r) * 64 + ch);
#pragma unroll
      for (int tm = 0; tm < 4; ++tm)
#pragma unroll
        for (int tn = 0; tn < NC; ++tn)
          acc[tm][tn] = __builtin_amdgcn_mfma_f32_16x16x32_bf16(af[tm], bfr[tn], acc[tm][tn], 0, 0, 0);
    }
  }
#undef STAGE
  float* dst = (float*)(SPLITX ? (kbeg > 0 ? C1v : C0v) : C0v);
  // C/D layout: col = lane&15, row = (lane>>4)*4 + reg   [guide §3, m89-verified]
#pragma unroll
  for (int tm = 0; tm < 4; ++tm) {
    int gr0 = row0 + wm * 64 + tm * 16 + q * 4;
#pragma unroll
    for (int tn = 0; tn < NC; ++tn) {
      int gc = col0 + wn * 16 * NC + tn * 16 + r;
#pragma unroll
      for (int p = 0; p < 4; ++p) {
        float vv = acc[tm][tn][p];
        if (RELU) vv = fmaxf(vv, 0.f);
        if (OUT_BF16) {
          ((__hip_bfloat16*)C0v)[(size_t)(gr0 + p) * N + gc] = __float2bfloat16(vv);
        } else {
          dst[(size_t)(gr0 + p) * N + gc] = vv;
          if (do_mirror) dst[(size_t)gc * N + (gr0 + p)] = vv;
        }
      }
    }
  }
}

// ---- 2b) gram split-K combiner: S += P1g (flat, both symmetric-complete) ----
__global__ void combine_add(float* __restrict__ S, const float* __restrict__ P) {
  int i = blockIdx.x * 256 + threadIdx.x;
  float4 a = ((const float4*)S)[i];
  float4 b = ((const float4*)P)[i];
  a.x += b.x;
  a.y += b.y;
  a.z += b.z;
  a.w += b.w;
  ((float4*)S)[i] = a;
}

// ------- 3) fused scan+repair: block = row i; LDS queue; 4 waves repair -----
__global__ __launch_bounds__(256) void scan_repair(float* __restrict__ S,
                                                   const float* __restrict__ xpt,
                                                   const float* __restrict__ Wpt,
                                                   const float* __restrict__ norms) {
  __shared__ int lqueue[2048];
  __shared__ int lcount;
  if (threadIdx.x == 0) lcount = 0;
  __syncthreads();
  const int row = blockIdx.x;
  const int base_idx = row * 2048;
#pragma unroll
  for (int t = 0; t < 2; ++t) {
    int col = t * 1024 + threadIdx.x * 4;
    if (col + 4 <= row) continue;  // whole float4 group below diagonal
    float4 v = *(const float4*)(S + base_idx + col);
    float vv[4] = {v.x, v.y, v.z, v.w};
#pragma unroll
    for (int u = 0; u < 4; ++u) {
      int j = col + u;
      if (j >= row && fabsf(vv[u] - 0.1f) < WINDOW) {
        int p = atomicAdd(&lcount, 1);  // LDS atomic
        lqueue[p] = j;
      }
    }
  }
  __syncthreads();
  const int n = lcount;
  if (n == 0) return;
  const int lane = threadIdx.x & 63;
  const int wave = threadIdx.x >> 6;
  const int i = row;
  float xiv[5];
  {
    const float* xi = xpt + i * EPT;
#pragma unroll
    for (int t = 0; t < 5; ++t) {
      int idx = lane + 64 * t;
      xiv[t] = idx < EPT ? xi[idx] : 0.f;
    }
  }
  for (int k = wave; k < n; k += 4) {  // waves take entries round-robin
    int j = lqueue[k];
    const float* xj = xpt + j * EPT;
    float pre[5];
#pragma unroll
    for (int t = 0; t < 5; ++t) {
      int idx = lane + 64 * t;
      pre[t] = idx < EPT ? xiv[t] * xj[idx] : 0.f;
    }
    float accv = 0.f;
#pragma unroll
    for (int h = 0; h < H_DIM; ++h) {
      float ph = 0.f;
#pragma unroll
      for (int t = 0; t < 5; ++t) {
        int idx = lane + 64 * t;
        if (idx < EPT) {
          float w = Wpt[h * EPT + idx];
          float w2 = w * w;
          ph += pre[t] * (w2 * w2);  // w^4 inline
        }
      }
      accv += ph * (1.f / (norms[i * H_DIM + h] * norms[j * H_DIM + h]));
    }
#pragma unroll
    for (int o = 32; o >= 1; o >>= 1) accv += __shfl_xor(accv, o, 64);
    if (lane == 0) {
      float val = accv * (1.f / 16.f);
      S[(size_t)i * L_DIM + j] = val;
      S[(size_t)j * L_DIM + i] = val;  // mirror: column i<j, unread by block j
    }
  }
}

// ------- 4) post: softmax->adj  +  label cast  +  W0/W1 transpose -----------
// grid 6656: [0,2048) softmax rows; [2048,6144) cast; [6144,6656) transpose.
__global__ __launch_bounds__(256) void post_kernel(const float* __restrict__ S,
                                                   __hip_bfloat16* __restrict__ adj,
                                                   const float* __restrict__ label,
                                                   __hip_bfloat16* __restrict__ Lbf,
                                                   const float* __restrict__ W0,
                                                   const float* __restrict__ W1,
                                                   __hip_bfloat16* __restrict__ W0t,
                                                   __hip_bfloat16* __restrict__ W1t) {
  __shared__ float red[4];
  __shared__ float tile[32][33];
  const int b = blockIdx.x;
  const int tid = threadIdx.x;
  if (b < 2048) {
    const int row = b;
    const float* s = S + (size_t)row * L_DIM;
    float m = -1e30f;
    for (int j = tid; j < L_DIM; j += 256) {
      float v = s[j];
      if (v >= 0.1f && v > m) m = v;
    }
#pragma unroll
    for (int o = 32; o >= 1; o >>= 1) m = fmaxf(m, __shfl_xor(m, o, 64));
    if ((tid & 63) == 0) red[tid >> 6] = m;
    __syncthreads();
    m = fmaxf(fmaxf(red[0], red[1]), fmaxf(red[2], red[3]));
    float sum = 0.f;
    for (int j = tid; j < L_DIM; j += 256) {
      float v = s[j];
      if (v >= 0.1f) sum += __expf(v - m);
    }
#pragma unroll
    for (int o = 32; o >= 1; o >>= 1) sum += __shfl_xor(sum, o, 64);
    __syncthreads();
    if ((tid & 63) == 0) red[tid >> 6] = sum;
    __syncthreads();
    sum = red[0] + red[1] + red[2] + red[3];
    float inv = 1.f / sum;
    for (int j = tid; j < L_DIM; j += 256) {
      float v = s[j];
      float a = (v >= 0.1f) ? __expf(v - m) * inv : 0.f;
      adj[(size_t)row * L_DIM + j] = __float2bfloat16(a);
    }
    return;
  }
  if (b < 6144) {
    int i = (b - 2048) * 256 + tid;
    Lbf[i] = __float2bfloat16(label[i]);
    return;
  }
  int local = b - 6144;
  const bool first = local < 256;
  const float* src = first ? W0 : W1;
  __hip_bfloat16* dst = first ? W0t : W1t;
  int rem = local & 255;
  int c0 = (rem & 15) * 32, r0 = (rem >> 4) * 32;
  int tx = tid & 31, ty = tid >> 5;
  for (int i2 = ty; i2 < 32; i2 += 8) tile[i2][tx] = src[(size_t)(r0 + i2) * 512 + c0 + tx];
  __syncthreads();
  for (int i2 = ty; i2 < 32; i2 += 8)
    dst[(size_t)(c0 + i2) * 512 + r0 + tx] = __float2bfloat16(tile[tx][i2]);
}

// ---------------- split-K combiners (R14-proven) ----------------
__global__ void combine_relu_bf16(const float* __restrict__ P0, const float* __restrict__ P1,
                                  __hip_bfloat16* __restrict__ X) {
  int i = blockIdx.x * 256 + threadIdx.x;
  float4 a = ((const float4*)P0)[i];
  float4 b = ((const float4*)P1)[i];
  __hip_bfloat16 o0 = __float2bfloat16(fmaxf(a.x + b.x, 0.f));
  __hip_bfloat16 o1 = __float2bfloat16(fmaxf(a.y + b.y, 0.f));
  __hip_bfloat16 o2 = __float2bfloat16(fmaxf(a.z + b.z, 0.f));
  __hip_bfloat16 o3 = __float2bfloat16(fmaxf(a.w + b.w, 0.f));
  X[4 * i + 0] = o0;
  X[4 * i + 1] = o1;
  X[4 * i + 2] = o2;
  X[4 * i + 3] = o3;
}

__global__ void combine_relu_f32(const float* __restrict__ P0, const float* __restrict__ P1,
                                 float* __restrict__ X) {
  int i = blockIdx.x * 256 + threadIdx.x;
  float4 a = ((const float4*)P0)[i];
  float4 b = ((const float4*)P1)[i];
  float4 v;
  v.x = fmaxf(a.x + b.x, 0.f);
  v.y = fmaxf(a.y + b.y, 0.f);
  v.z = fmaxf(a.z + b.z, 0.f);
  v.w = fmaxf(a.w + b.w, 0.f);
  ((float4*)X)[i] = v;
}

extern "C" void kernel_launch(void* const* d_in, const int* in_sizes, int n_in, void* d_out,
                              int out_size, void* d_ws, size_t ws_size, hipStream_t stream) {
  const float* label = (const float*)d_in[0];  // [2048,512]
  const float* xpt = (const float*)d_in[1];    // [2048,300]
  const float* Wpt = (const float*)d_in[2];    // [16,300]
  const float* W0 = (const float*)d_in[3];     // [512,512]
  const float* W1 = (const float*)d_in[4];     // [512,512]
  float* out = (float*)d_out;                  // [2048,512]

  // ---- layout (peak 53.35MB; ws >= 53.4MB proven by R12's split run) ----
  char* ws = (char*)d_ws;
  __hip_bfloat16* Y = (__hip_bfloat16*)ws;              // [0, 19,660,800) live thru gram
  float* S = (float*)(ws + 19660800);                   // [19,660,800, 36,438,016)
  float* P1g = (float*)(ws + 36438016);                 // 16MB gram partial -> ends 53,215,232
  float* norms = (float*)(ws + 53215232);               // 128KB -> ends 53,346,304
  float* P0 = (float*)(ws + 36569088);                  // 4MB partial (after P1g dead)
  float* P1 = (float*)(ws + 40763392);                  // 4MB -> ends 44,957,696
  __hip_bfloat16* adj = (__hip_bfloat16*)ws;            // [0, 8,388,608) after softmax
  // GCN temporaries in the dead-Y window [8.39MB, 17.83MB):
  __hip_bfloat16* Lbf = (__hip_bfloat16*)(ws + 8388608);    // 2MB
  __hip_bfloat16* W0t = (__hip_bfloat16*)(ws + 10485760);   // 0.5MB
  __hip_bfloat16* W1t = (__hip_bfloat16*)(ws + 11010048);   // 0.5MB
  __hip_bfloat16* T0t = (__hip_bfloat16*)(ws + 11534336);   // 2MB [512x2048]
  __hip_bfloat16* X1 = (__hip_bfloat16*)(ws + 13631488);    // 2MB [2048x512]
  __hip_bfloat16* T1t = (__hip_bfloat16*)(ws + 15728640);   // 2MB -> ends 17,825,792

  compute_y_kernel<<<8192, 256, 0, stream>>>(xpt, Wpt, Y, norms);
  // S = Y Y^T: 64x64 triangle+mirror + split-K=2 (SPLITX x-fold):
  //   1056 live blocks (~4.1/CU vs 2.06 before) -> partials in S and P1g
  gemm_bt<64, 64, false, false, true, true><<<dim3(64, 32), 256, 0, stream>>>(Y, Y, S, P1g, 2048, 2048, KDIM);
  // S += P1g (both halves wrote full symmetric tiles incl. mirrors)
  combine_add<<<4096, 256, 0, stream>>>(S, P1g);
  // fused borderline scan + exact-f32 repair (row-owned; no global list)
  scan_repair<<<2048, 256, 0, stream>>>(S, xpt, Wpt, norms);
  // softmax -> adj + label cast + W transposes (one launch)
  post_kernel<<<6656, 256, 0, stream>>>(S, adj, label, Lbf, W0, W1, W0t, W1t);
  // T0t = (label@W0)^T = W0t * Lbf^T   [512 x 2048]
  gemm_bt<64, 64, false, true, false, false><<<dim3(32, 8), 256, 0, stream>>>(W0t, Lbf, T0t, nullptr, 512, 2048, 512);
  // X1 = relu(adj @ T0): split-K=2 (x-folded, 512 blocks) -> P0/P1, combine
  gemm_bt<64, 64, false, false, false, true><<<dim3(16, 32), 256, 0, stream>>>(adj, T0t, P0, P1, 2048, 512, 2048);
  combine_relu_bf16<<<1024, 256, 0, stream>>>(P0, P1, X1);
  // T1t = (X1@W1)^T = W1t * X1^T   [512 x 2048]
  gemm_bt<64, 64, false, true, false, false><<<dim3(32, 8), 256, 0, stream>>>(W1t, X1, T1t, nullptr, 512, 2048, 512);
  // out = relu(adj @ T1): split-K=2 -> P0/P1, combine into d_out
  gemm_bt<64, 64, false, false, false, true><<<dim3(16, 32), 256, 0, stream>>>(adj, T1t, P0, P1, 2048, 512, 2048);
  combine_relu_f32<<<1024, 256, 0, stream>>>(P0, P1, out);
}